// Round 7
// baseline (582.903 us; speedup 1.0000x reference)
//
#include <hip/hip_runtime.h>
#include <stdint.h>

#define NPATHS 4096
#define LPATH  8
#define DIM    256
#define HID    256
#define NBLK   256

typedef short  short4v __attribute__((ext_vector_type(4)));
typedef short  short8v __attribute__((ext_vector_type(8)));
typedef float  float4v __attribute__((ext_vector_type(4)));

__device__ __forceinline__ unsigned short f2bf(float f) {
    union { float f; uint32_t u; } v; v.f = f;
    uint32_t u = v.u;
    u += 0x7FFFu + ((u >> 16) & 1u);   // round-to-nearest-even
    return (unsigned short)(u >> 16);
}
__device__ __forceinline__ float fast_sigmoid(float x) {
    return 1.0f / (1.0f + __expf(-x));
}
__device__ __forceinline__ float fast_tanh(float x) {
    x = fminf(15.0f, fmaxf(-15.0f, x));
    float e = __expf(2.0f * x);
    return (e - 1.0f) / (e + 1.0f);
}
// monotone float<->uint encoding for atomicMax over signed floats
__device__ __forceinline__ unsigned int encf(float f) {
    unsigned int u = __float_as_uint(f);
    return (u & 0x80000000u) ? ~u : (u | 0x80000000u);
}
__device__ __forceinline__ float decf(unsigned int u) {
    return (u & 0x80000000u) ? __uint_as_float(u & 0x7FFFFFFFu) : __uint_as_float(~u);
}

// async global->LDS DMA, 16 B/lane (global_load_lds_dwordx4).
__device__ __forceinline__ void dma16(void* lds, const void* g) {
    typedef const unsigned int __attribute__((address_space(1)))* gp_t;
    typedef unsigned int __attribute__((address_space(3)))* lp_t;
    gp_t gp = reinterpret_cast<gp_t>(reinterpret_cast<uintptr_t>(g));
    lp_t lp = reinterpret_cast<lp_t>(static_cast<unsigned int>(reinterpret_cast<uintptr_t>(lds)));
    __builtin_amdgcn_global_load_lds(gp, lp, 16, 0, 0);
}

// Hand-rolled grid barrier (sense-reversing, device-scope). Safe because the
// persistent kernel is provably fully co-resident: 256 blocks, 1/CU, 256 CUs
// (64 KB LDS + ~400 VGPR cap a CU at 1 block). Coop launch is broken in this
// harness (R3-R5: silent no-launch), so we do what cg::grid_group does by hand.
__device__ __forceinline__ void grid_barrier(unsigned int* cnt, unsigned int* gen, int tid) {
    __syncthreads();
    if (tid == 0) {
        __threadfence();   // release: drain stores, wb L2 (agent scope)
        unsigned int g = __hip_atomic_load(gen, __ATOMIC_RELAXED, __HIP_MEMORY_SCOPE_AGENT);
        unsigned int a = __hip_atomic_fetch_add(cnt, 1u, __ATOMIC_ACQ_REL, __HIP_MEMORY_SCOPE_AGENT);
        if (a == NBLK - 1) {
            __hip_atomic_store(cnt, 0u, __ATOMIC_RELAXED, __HIP_MEMORY_SCOPE_AGENT);
            __hip_atomic_fetch_add(gen, 1u, __ATOMIC_ACQ_REL, __HIP_MEMORY_SCOPE_AGENT);
        } else {
            while (__hip_atomic_load(gen, __ATOMIC_RELAXED, __HIP_MEMORY_SCOPE_AGENT) == g)
                __builtin_amdgcn_s_sleep(2);
        }
        __threadfence();   // acquire: invalidate L1 + stale L2 lines
    }
    __syncthreads();
}

// ---------------------------------------------------------------------------
// K0: pack weights into B-fragment order + bias + zero logits/path_emb/barrier
// (blocks 0..511); gather+convert embeddings to Xb (blocks 512..8703).
// WfB (shorts): [(g*16+kc)][unit][quad*8+j] -> step wave load is coalesced.
// ---------------------------------------------------------------------------
__global__ void prep_gather(const float* __restrict__ w_ih, const float* __restrict__ w_hh,
                            const float* __restrict__ b_ih, const float* __restrict__ b_hh,
                            const float* __restrict__ embedding, const int* __restrict__ paths,
                            unsigned short* __restrict__ WfB, float* __restrict__ bias,
                            unsigned int* __restrict__ logits_enc, float* __restrict__ path_emb,
                            unsigned short* __restrict__ Xb, unsigned int* __restrict__ bar) {
    int bid = blockIdx.x;
    if (bid < 512) {
        int gid  = bid * 256 + threadIdx.x;    // 0..131071
        int base = gid * 4;                    // short index, %4==0
        int j0   = base & 31;                  // quad*8+j
        int unit = (base >> 5) & 255;
        int gkc  = base >> 13;                 // g*16+kc, 0..63
        int g    = gkc >> 4, kc = gkc & 15;
        int row  = g * 256 + unit;
        int k    = kc * 32 + j0;
        const float* src = (k < DIM) ? (w_ih + (size_t)row * DIM + k)
                                     : (w_hh + (size_t)row * HID + (k - DIM));
        float4 v = *(const float4*)src;
        short4v pk = {(short)f2bf(v.x), (short)f2bf(v.y), (short)f2bf(v.z), (short)f2bf(v.w)};
        *(short4v*)(WfB + base) = pk;
        if (gid < 1024) bias[gid] = b_ih[gid] + b_hh[gid];
        if (gid < NPATHS) logits_enc[gid] = 0u;
        if (gid < 256) path_emb[gid] = 0.0f;
        if (gid < 2) bar[gid] = 0u;            // barrier cnt/gen (ws is poisoned!)
    } else {
        int gid  = (bid - 512) * 256 + threadIdx.x;  // 0..2097151
        int rowt = gid >> 6;                         // t*4096 + p
        int seg  = gid & 63;
        int p    = rowt & (NPATHS - 1);
        int t    = rowt >> 12;
        int node = paths[p * LPATH + t];
        float4 v = *(const float4*)(embedding + (size_t)node * DIM + seg * 4);
        short4v pk = {(short)f2bf(v.x), (short)f2bf(v.y), (short)f2bf(v.z), (short)f2bf(v.w)};
        *(short4v*)(Xb + (size_t)rowt * DIM + seg * 4) = pk;
    }
}

// ---------------------------------------------------------------------------
// K1 (persistent): 8 LSTM steps + softmax + attention + head, one dispatch.
// 256 blocks x 256 threads, 64 KB static LDS, normal launch + hand barrier.
// Block = (ptile 0..63, utile 0..3): paths p0..p0+63, units u0..u0+63;
//   blk%8 = ptile%8 (a ptile's 4 blocks share an XCD for h/Xb L2 locality).
// Wave w: 16 units (u0+w*16+l15), all 4 gates -> i,f,g,o same-lane.
//   Bf 256 VGPRs loaded ONCE; c,h in regs for all 8 steps (no c traffic).
// sA = 64x512 [x_t|h] tile in MFMA-fragment order (frag-uniform dma16 dests,
//   one __syncthreads per step, conflict-free ds_read_b128 kc iters).
// hT/red alias sA behind barriers.
// ---------------------------------------------------------------------------
__global__ __launch_bounds__(256, 1)
void lstm_persist(const unsigned short* __restrict__ Xb,     // [8][4096][256]
                  const unsigned short* __restrict__ WfB,
                  const float* __restrict__ bias,
                  unsigned short* __restrict__ h_buf,        // [2][4096][256] bf16
                  unsigned int* __restrict__ logits_enc,     // [4096]
                  float* __restrict__ pw,                    // [4096]
                  float* __restrict__ path_emb,              // [256]
                  const float* __restrict__ embedding,
                  const int* __restrict__ user_id,
                  const int* __restrict__ item_id,
                  const float* __restrict__ w_lin,
                  const float* __restrict__ b_lin,
                  float* __restrict__ out,
                  unsigned int* __restrict__ bar) {
    __shared__ __align__(16) short sA[64 * 512];   // 64 frags x 64 lanes x 8 shorts
    short* hT  = sA;                               // alias: [64][72] shorts (guarded)
    float* red = (float*)sA;                       // alias: [256] fp32 (guarded)
    unsigned int* bcnt = bar;
    unsigned int* bgen = bar + 1;

    const int tid   = threadIdx.x;
    const int wave  = tid >> 6;
    const int lane  = tid & 63;
    const int l15   = lane & 15;
    const int quad  = lane >> 4;
    const int blk   = blockIdx.x;
    const int ptile = blk & 63;
    const int utile = blk >> 6;
    const int p0    = ptile * 64;
    const int u0    = utile * 64;

    // ---- persistent B fragments + bias (coalesced, once) ----
    short8v Bf[4][16];
    float bb[4];
    const int unit = u0 + wave * 16 + l15;
#pragma unroll
    for (int g = 0; g < 4; ++g) {
        bb[g] = bias[g * 256 + unit];
#pragma unroll
        for (int kc = 0; kc < 16; ++kc)
            Bf[g][kc] = *(const short8v*)(WfB + (((g * 16 + kc) * 256 + unit) * 32 + quad * 8));
    }

    float c_reg[16], h_reg[16];
#pragma unroll
    for (int i = 0; i < 16; ++i) c_reg[i] = 0.0f;

    for (int t = 0; t < LPATH; ++t) {
        // ---- A staging in fragment order (16B dma16, frag-uniform dests) ----
        {
            const char* xpl = (const char*)Xb + ((size_t)t * NPATHS + p0) * 512;
            const char* hpl = (const char*)h_buf + ((size_t)(t & 1) * NPATHS + p0) * 512;
            const char* xl  = xpl + l15 * 512 + quad * 16;
            const char* hl  = hpl + l15 * 512 + quad * 16;
#pragma unroll
            for (int m = 0; m < 16; ++m) {
                int rf = m >> 2, kq = m & 3;
                if (t == 0 && kq >= 2) continue;     // h==0 at t=0
                int fp = rf * 16 + kq * 4 + wave;    // frag id (wave-uniform)
                const char* base = (kq < 2) ? xl : hl;
                int kk = ((kq & 1) * 4 + wave) * 64;
                dma16(sA + fp * 512, base + rf * 8192 + kk);
            }
        }
        __syncthreads();   // tile resident

        // ---- MFMA: 64 paths x 256 gate-cols ----
        float4v acc[4][4];
        const float4v z4 = {0.0f, 0.0f, 0.0f, 0.0f};
#pragma unroll
        for (int rf = 0; rf < 4; ++rf)
#pragma unroll
            for (int g = 0; g < 4; ++g) acc[rf][g] = z4;

        auto kstep = [&](int kc) {
#pragma unroll
            for (int rf = 0; rf < 4; ++rf) {
                short8v a = *(const short8v*)(sA + ((rf * 16 + kc) << 9) + lane * 8);
#pragma unroll
                for (int g = 0; g < 4; ++g)
                    acc[rf][g] = __builtin_amdgcn_mfma_f32_16x16x32_bf16(
                        a, Bf[g][kc], acc[rf][g], 0, 0, 0);
            }
        };
        const int nkc = (t == 0) ? 8 : 16;
        for (int kc = 0; kc < nkc; ++kc) kstep(kc);

        // ---- pointwise LSTM update (register-local) ----
#pragma unroll
        for (int rf = 0; rf < 4; ++rf) {
#pragma unroll
            for (int r = 0; r < 4; ++r) {
                int idx = rf * 4 + r;
                float iv = acc[rf][0][r] + bb[0];
                float fv = acc[rf][1][r] + bb[1];
                float gv = acc[rf][2][r] + bb[2];
                float ov = acc[rf][3][r] + bb[3];
                float cn = fast_sigmoid(fv) * c_reg[idx]
                         + fast_sigmoid(iv) * fast_tanh(gv);
                c_reg[idx] = cn;
                h_reg[idx] = fast_sigmoid(ov) * fast_tanh(cn);
            }
        }

        if (t < LPATH - 1) {
            __syncthreads();   // all waves done reading sA before hT alias-write
#pragma unroll
            for (int rf = 0; rf < 4; ++rf)
#pragma unroll
                for (int r = 0; r < 4; ++r)
                    hT[(rf * 16 + quad * 4 + r) * 72 + wave * 16 + l15] =
                        (short)f2bf(h_reg[rf * 4 + r]);
            __syncthreads();
            // coalesced write: h_buf[(t+1)&1][p0+row][u0 + 0..63]
            unsigned short* hdst = h_buf + (size_t)((t + 1) & 1) * NPATHS * HID
                                 + (size_t)p0 * HID + u0;
#pragma unroll
            for (int i = 0; i < 2; ++i) {
                int cid = i * 256 + tid;
                int row = cid >> 3, seg = cid & 7;
                short8v v = *(const short8v*)(hT + row * 72 + seg * 8);
                *(short8v*)(hdst + (size_t)row * HID + seg * 8) = v;
            }
        } else {
            // attention logits: per-path max over this wave's 16 units
#pragma unroll
            for (int idx = 0; idx < 16; ++idx) {
                float m = h_reg[idx];
                m = fmaxf(m, __shfl_xor(m, 1, 64));
                m = fmaxf(m, __shfl_xor(m, 2, 64));
                m = fmaxf(m, __shfl_xor(m, 4, 64));
                m = fmaxf(m, __shfl_xor(m, 8, 64));
                if (l15 == 0) {
                    int rf = idx >> 2, r = idx & 3;
                    atomicMax(&logits_enc[p0 + rf * 16 + quad * 4 + r], encf(m));
                }
            }
        }
        grid_barrier(bcnt, bgen, tid);   // h / logits visible grid-wide
    }

    // ---- softmax over 4096 logits (block 0) ----
    if (blk == 0) {
        float vals[16];
        float m = -1e30f;
#pragma unroll
        for (int i = 0; i < 16; ++i) {
            vals[i] = decf(logits_enc[i * 256 + tid]);
            m = fmaxf(m, vals[i]);
        }
        red[tid] = m; __syncthreads();
        for (int s = 128; s > 0; s >>= 1) {
            if (tid < s) red[tid] = fmaxf(red[tid], red[tid + s]);
            __syncthreads();
        }
        m = red[0]; __syncthreads();
        float e[16];
        float sum = 0.0f;
#pragma unroll
        for (int i = 0; i < 16; ++i) { e[i] = __expf(vals[i] - m); sum += e[i]; }
        red[tid] = sum; __syncthreads();
        for (int s = 128; s > 0; s >>= 1) {
            if (tid < s) red[tid] += red[tid + s];
            __syncthreads();
        }
        float invZ = 1.0f / red[0];
#pragma unroll
        for (int i = 0; i < 16; ++i) pw[i * 256 + tid] = e[i] * invZ;
    }
    grid_barrier(bcnt, bgen, tid);

    // ---- attention-weighted sum from registers ----
    {
        float s = 0.0f;
#pragma unroll
        for (int rf = 0; rf < 4; ++rf)
#pragma unroll
            for (int r = 0; r < 4; ++r)
                s += pw[p0 + rf * 16 + quad * 4 + r] * h_reg[rf * 4 + r];
        s += __shfl_xor(s, 16, 64);   // reduce across quads (same unit)
        s += __shfl_xor(s, 32, 64);
        if (quad == 0) atomicAdd(&path_emb[unit], s);
    }
    grid_barrier(bcnt, bgen, tid);

    // ---- final head (block 0) ----
    if (blk == 0) {
        int u  = user_id[0];
        int it = item_id[0];
        float s = w_lin[tid]       * embedding[(size_t)u  * DIM + tid]
                + w_lin[256 + tid] * embedding[(size_t)it * DIM + tid]
                + w_lin[512 + tid] * path_emb[tid];
        red[tid] = s; __syncthreads();
        for (int st = 128; st > 0; st >>= 1) {
            if (tid < st) red[tid] += red[tid + st];
            __syncthreads();
        }
        if (tid == 0) out[0] = 1.0f / (1.0f + __expf(-(red[0] + b_lin[0])));
    }
}

// ---------------------------------------------------------------------------
extern "C" void kernel_launch(void* const* d_in, const int* in_sizes, int n_in,
                              void* d_out, int out_size, void* d_ws, size_t ws_size,
                              hipStream_t stream) {
    const float* embedding = (const float*)d_in[0];
    const float* w_ih      = (const float*)d_in[1];
    const float* w_hh      = (const float*)d_in[2];
    const float* b_ih      = (const float*)d_in[3];
    const float* b_hh      = (const float*)d_in[4];
    const float* w_lin     = (const float*)d_in[5];
    const float* b_lin     = (const float*)d_in[6];
    const int*   paths     = (const int*)d_in[7];
    const int*   user_id   = (const int*)d_in[8];
    const int*   item_id   = (const int*)d_in[9];
    float* outp = (float*)d_out;

    // workspace layout (~21.1 MB), 256-B aligned
    char* ws = (char*)d_ws;
    size_t off = 0;
    auto alloc = [&](size_t n) { void* p = ws + off; off = (off + n + 255) & ~(size_t)255; return p; };
    unsigned short* WfB       = (unsigned short*)alloc((size_t)1024 * 512 * 2);           // 1 MB
    float*          bias      = (float*)alloc(1024 * 4);                                  // 4 KB
    unsigned int*   logits_enc= (unsigned int*)alloc(NPATHS * 4);                         // 16 KB
    float*          pw        = (float*)alloc(NPATHS * 4);                                // 16 KB
    float*          path_emb  = (float*)alloc(HID * 4);                                   // 1 KB
    unsigned int*   bar       = (unsigned int*)alloc(256);                                // cnt,gen
    unsigned short* Xb        = (unsigned short*)alloc((size_t)LPATH * NPATHS * DIM * 2); // 16 MB
    unsigned short* h_buf     = (unsigned short*)alloc((size_t)2 * NPATHS * HID * 2);     // 4 MB

    prep_gather<<<8704, 256, 0, stream>>>(w_ih, w_hh, b_ih, b_hh, embedding, paths,
                                          WfB, bias, logits_enc, path_emb, Xb, bar);

    lstm_persist<<<NBLK, 256, 0, stream>>>(Xb, WfB, bias, h_buf, logits_enc, pw, path_emb,
                                           embedding, user_id, item_id, w_lin, b_lin,
                                           outp, bar);
}

// Round 8
// 272.755 us; speedup vs baseline: 2.1371x; 2.1371x over previous
//
#include <hip/hip_runtime.h>
#include <stdint.h>

#define NPATHS 4096
#define LPATH  8
#define DIM    256
#define HID    256

typedef short  short4v __attribute__((ext_vector_type(4)));
typedef short  short8v __attribute__((ext_vector_type(8)));
typedef float  float4v __attribute__((ext_vector_type(4)));

__device__ __forceinline__ unsigned short f2bf(float f) {
    union { float f; uint32_t u; } v; v.f = f;
    uint32_t u = v.u;
    u += 0x7FFFu + ((u >> 16) & 1u);   // round-to-nearest-even
    return (unsigned short)(u >> 16);
}
__device__ __forceinline__ float bf2f(unsigned short s) {
    return __uint_as_float(((uint32_t)s) << 16);
}
__device__ __forceinline__ float fast_sigmoid(float x) {
    return 1.0f / (1.0f + __expf(-x));
}
__device__ __forceinline__ float fast_tanh(float x) {
    x = fminf(15.0f, fmaxf(-15.0f, x));
    float e = __expf(2.0f * x);
    return (e - 1.0f) / (e + 1.0f);
}
// monotone float<->uint encoding for atomicMax over signed floats
__device__ __forceinline__ unsigned int encf(float f) {
    unsigned int u = __float_as_uint(f);
    return (u & 0x80000000u) ? ~u : (u | 0x80000000u);
}
__device__ __forceinline__ float decf(unsigned int u) {
    return (u & 0x80000000u) ? __uint_as_float(u & 0x7FFFFFFFu) : __uint_as_float(~u);
}

// async global->LDS DMA, 16 B/lane (global_load_lds_dwordx4).
// Global addresses are per-lane; LDS dest is wave-uniform base + lane*16.
__device__ __forceinline__ void dma16(void* lds, const void* g) {
    typedef const unsigned int __attribute__((address_space(1)))* gp_t;
    typedef unsigned int __attribute__((address_space(3)))* lp_t;
    gp_t gp = reinterpret_cast<gp_t>(reinterpret_cast<uintptr_t>(g));
    lp_t lp = reinterpret_cast<lp_t>(static_cast<unsigned int>(reinterpret_cast<uintptr_t>(lds)));
    __builtin_amdgcn_global_load_lds(gp, lp, 16, 0, 0);
}

// ---------------------------------------------------------------------------
// K0 (combined): blocks 0..511 pack weights into B-fragment order + bias +
// zero logits/path_emb; blocks 512..8703 gather+convert embeddings to Xb.
// WfB (shorts): [(g*16+kc)][unit][quad*8+j] -> step wave load is coalesced.
// ---------------------------------------------------------------------------
__global__ void prep_gather(const float* __restrict__ w_ih, const float* __restrict__ w_hh,
                            const float* __restrict__ b_ih, const float* __restrict__ b_hh,
                            const float* __restrict__ embedding, const int* __restrict__ paths,
                            unsigned short* __restrict__ WfB, float* __restrict__ bias,
                            unsigned int* __restrict__ logits_enc, float* __restrict__ path_emb,
                            unsigned short* __restrict__ Xb) {
    int bid = blockIdx.x;
    if (bid < 512) {
        int gid  = bid * 256 + threadIdx.x;    // 0..131071
        int base = gid * 4;                    // short index, %4==0
        int j0   = base & 31;                  // quad*8+j
        int unit = (base >> 5) & 255;
        int gkc  = base >> 13;                 // g*16+kc, 0..63
        int g    = gkc >> 4, kc = gkc & 15;
        int row  = g * 256 + unit;
        int k    = kc * 32 + j0;
        const float* src = (k < DIM) ? (w_ih + (size_t)row * DIM + k)
                                     : (w_hh + (size_t)row * HID + (k - DIM));
        float4 v = *(const float4*)src;
        short4v pk = {(short)f2bf(v.x), (short)f2bf(v.y), (short)f2bf(v.z), (short)f2bf(v.w)};
        *(short4v*)(WfB + base) = pk;
        if (gid < 1024) bias[gid] = b_ih[gid] + b_hh[gid];
        if (gid < NPATHS) logits_enc[gid] = 0u;
        if (gid < 256) path_emb[gid] = 0.0f;
    } else {
        int gid  = (bid - 512) * 256 + threadIdx.x;  // 0..2097151
        int rowt = gid >> 6;                         // t*4096 + p
        int seg  = gid & 63;
        int p    = rowt & (NPATHS - 1);
        int t    = rowt >> 12;
        int node = paths[p * LPATH + t];
        float4 v = *(const float4*)(embedding + (size_t)node * DIM + seg * 4);
        short4v pk = {(short)f2bf(v.x), (short)f2bf(v.y), (short)f2bf(v.z), (short)f2bf(v.w)};
        *(short4v*)(Xb + (size_t)rowt * DIM + seg * 4) = pk;
    }
}

// ---------------------------------------------------------------------------
// K1..K8: one LSTM step. 256 blocks x 256 threads, 64 KB static LDS.
// Block = (ptile 0..63, utile 0..3): paths p0..p0+63, units u0..u0+63.
//   blk%8 = ptile%8 (a ptile's 4 blocks share an XCD for h/Xb L2 locality).
// Wave w: 16 units (u0+w*16+l15), all 4 gates, all 64 path rows.
//   B: 4 gates x 16 kc x short8 = 256 VGPRs, loaded coalesced from WfB.
//   i,f,g,o of one (path,unit) land in the SAME lane -> register pointwise.
// sA = 64x512 [x_t|h] tile in MFMA-fragment order [frag][lane][16B]:
//   one dma16 per frag (wave-uniform dest), ONE barrier, then 16 kc iters of
//   conflict-free ds_read_b128.  c: global fp32 [path][unit].
// h written coalesced via hT transpose (aliases sA behind a barrier).
// NOTE (R7 lesson): do NOT fuse steps with in-kernel grid barriers — agent
// fences writeback/invalidate all 8 per-XCD L2s (~40 µs each, 260 MB refetch).
// Kernel-boundary sync keeps L2 warm and costs only the ~2-3 µs launch gap.
// ---------------------------------------------------------------------------
template<bool FIRST, bool LAST>
__global__ __launch_bounds__(256, 1)
void step_kernel(const unsigned short* __restrict__ Xb,     // [8][4096][256]
                 const unsigned short* __restrict__ WfB,    // frag-ordered
                 const float* __restrict__ bias,            // [1024]
                 const unsigned short* __restrict__ h_in,   // [4096][256] bf16
                 unsigned short* __restrict__ h_out,        // [4096][256] bf16
                 float* __restrict__ c_g,                   // [4096][256] fp32
                 unsigned int* __restrict__ logits_enc,     // [4096] (LAST)
                 int t) {
    __shared__ __align__(16) short sA[64 * 512];   // 64 frags x 64 lanes x 8 shorts
    short* hT = sA;                                // alias: [64][72] shorts (guarded)

    const int tid   = threadIdx.x;
    const int wave  = tid >> 6;
    const int lane  = tid & 63;
    const int l15   = lane & 15;
    const int quad  = lane >> 4;
    const int blk   = blockIdx.x;
    const int ptile = blk & 63;
    const int utile = blk >> 6;
    const int p0    = ptile * 64;
    const int u0    = utile * 64;

    // ---- A staging: 16 dma16/thread in fragment order ----
    {
        const char* xpl = (const char*)Xb + ((size_t)t * NPATHS + p0) * 512;
        const char* hpl = (const char*)h_in + (size_t)p0 * 512;
        const char* xl  = xpl + l15 * 512 + quad * 16;
        const char* hl  = hpl + l15 * 512 + quad * 16;
#pragma unroll
        for (int m = 0; m < 16; ++m) {
            int rf = m >> 2, kq = m & 3;
            if (FIRST && kq >= 2) continue;          // h==0 at t=0
            int fp = rf * 16 + kq * 4 + wave;        // frag id, wave-uniform
            const char* base = (kq < 2) ? xl : hl;
            int kk = ((kq & 1) * 4 + wave) * 64;     // (kc&7)*64 bytes in row
            dma16(sA + fp * 512, base + rf * 8192 + kk);
        }
    }

    // ---- B fragments + bias (registers, coalesced loads; overlap w/ DMA) ----
    short8v Bf[4][16];
    float bb[4];
    const int unit = u0 + wave * 16 + l15;
#pragma unroll
    for (int g = 0; g < 4; ++g) {
        bb[g] = bias[g * 256 + unit];
#pragma unroll
        for (int kc = 0; kc < 16; ++kc)
            Bf[g][kc] = *(const short8v*)(WfB + (((g * 16 + kc) * 256 + unit) * 32 + quad * 8));
    }

    __syncthreads();   // single vmcnt drain: tile resident

    // ---- MFMA: 64 paths x 256 gate-cols, K=512 (256 at t=0) ----
    float4v acc[4][4];
    const float4v z4 = {0.0f, 0.0f, 0.0f, 0.0f};
#pragma unroll
    for (int rf = 0; rf < 4; ++rf)
#pragma unroll
        for (int g = 0; g < 4; ++g) acc[rf][g] = z4;

    auto kstep = [&](int kc) {
#pragma unroll
        for (int rf = 0; rf < 4; ++rf) {
            short8v a = *(const short8v*)(sA + ((rf * 16 + kc) << 9) + lane * 8);
#pragma unroll
            for (int g = 0; g < 4; ++g)
                acc[rf][g] = __builtin_amdgcn_mfma_f32_16x16x32_bf16(
                    a, Bf[g][kc], acc[rf][g], 0, 0, 0);
        }
    };
    if (FIRST) {
#pragma unroll
        for (int kc = 0; kc < 8; ++kc) kstep(kc);
    } else {
#pragma unroll
        for (int kc = 0; kc < 16; ++kc) kstep(kc);
    }

    // ---- pointwise LSTM update (i,f,g,o same-lane) ----
    float hv[16];
#pragma unroll
    for (int rf = 0; rf < 4; ++rf) {
#pragma unroll
        for (int r = 0; r < 4; ++r) {
            int row = rf * 16 + quad * 4 + r;       // block-local path row
            int idx = rf * 4 + r;
            float iv = acc[rf][0][r] + bb[0];
            float fv = acc[rf][1][r] + bb[1];
            float gv = acc[rf][2][r] + bb[2];
            float ov = acc[rf][3][r] + bb[3];
            size_t coff = (size_t)(p0 + row) * HID + unit;
            float cp = FIRST ? 0.0f : c_g[coff];
            float cn = fast_sigmoid(fv) * cp + fast_sigmoid(iv) * fast_tanh(gv);
            if (!LAST) c_g[coff] = cn;
            hv[idx] = fast_sigmoid(ov) * fast_tanh(cn);
        }
    }

    // ---- coalesced h write via hT transpose (sA free after kc loop) ----
    __syncthreads();   // all waves done reading sA
#pragma unroll
    for (int rf = 0; rf < 4; ++rf)
#pragma unroll
        for (int r = 0; r < 4; ++r)
            hT[(rf * 16 + quad * 4 + r) * 72 + wave * 16 + l15] =
                (short)f2bf(hv[rf * 4 + r]);
    __syncthreads();
    {
        unsigned short* hdst = h_out + (size_t)p0 * HID + u0;
#pragma unroll
        for (int i = 0; i < 2; ++i) {
            int cid = i * 256 + tid;              // 0..511
            int row = cid >> 3, seg = cid & 7;
            short8v v = *(const short8v*)(hT + row * 72 + seg * 8);
            *(short8v*)(hdst + (size_t)row * HID + seg * 8) = v;
        }
    }

    if (LAST) {
        // per-path max over this wave's 16 units -> atomicMax (encoded)
#pragma unroll
        for (int idx = 0; idx < 16; ++idx) {
            float m = hv[idx];
            m = fmaxf(m, __shfl_xor(m, 1, 64));
            m = fmaxf(m, __shfl_xor(m, 2, 64));
            m = fmaxf(m, __shfl_xor(m, 4, 64));
            m = fmaxf(m, __shfl_xor(m, 8, 64));
            if (l15 == 0) {
                int rf = idx >> 2, r = idx & 3;
                atomicMax(&logits_enc[p0 + rf * 16 + quad * 4 + r], encf(m));
            }
        }
    }
}

// ---------------------------------------------------------------------------
// K9: fused softmax + attention partial sums. 256 blocks x 256 threads;
// each block redundantly computes the global softmax scalars from the 16 KB
// logits array (L2-resident), then accumulates its 16 paths into path_emb.
// ---------------------------------------------------------------------------
__global__ void attn_sum_kernel(const unsigned short* __restrict__ h_final,
                                const unsigned int* __restrict__ enc,
                                float* __restrict__ path_emb) {
    __shared__ float red[256];
    __shared__ float wts[16];
    int tid = threadIdx.x;
    int p0  = blockIdx.x * 16;

    float vals[16];
    float m = -1e30f;
#pragma unroll
    for (int i = 0; i < 16; ++i) {
        vals[i] = decf(enc[i * 256 + tid]);
        m = fmaxf(m, vals[i]);
    }
    red[tid] = m; __syncthreads();
    for (int s = 128; s > 0; s >>= 1) {
        if (tid < s) red[tid] = fmaxf(red[tid], red[tid + s]);
        __syncthreads();
    }
    m = red[0]; __syncthreads();
    float sum = 0.0f;
#pragma unroll
    for (int i = 0; i < 16; ++i) sum += __expf(vals[i] - m);
    red[tid] = sum; __syncthreads();
    for (int s = 128; s > 0; s >>= 1) {
        if (tid < s) red[tid] += red[tid + s];
        __syncthreads();
    }
    if (tid == 0) red[0] = 1.0f / red[0];
    __syncthreads();
    float invZ = red[0];
    if (tid < 16) wts[tid] = __expf(decf(enc[p0 + tid]) - m) * invZ;
    __syncthreads();

    float acc = 0.0f;
#pragma unroll
    for (int j = 0; j < 16; ++j)
        acc += wts[j] * bf2f(h_final[(size_t)(p0 + j) * HID + tid]);
    atomicAdd(&path_emb[tid], acc);
}

// ---------------------------------------------------------------------------
// K10: out = sigmoid([user|item|path_emb] . w_lin + b_lin)
// ---------------------------------------------------------------------------
__global__ void final_kernel(const float* __restrict__ embedding,
                             const int* __restrict__ user_id,
                             const int* __restrict__ item_id,
                             const float* __restrict__ w_lin,
                             const float* __restrict__ b_lin,
                             const float* __restrict__ path_emb,
                             float* __restrict__ out) {
    __shared__ float red[256];
    int tid = threadIdx.x;
    int u  = user_id[0];
    int it = item_id[0];
    float s = w_lin[tid]       * embedding[(size_t)u  * DIM + tid]
            + w_lin[256 + tid] * embedding[(size_t)it * DIM + tid]
            + w_lin[512 + tid] * path_emb[tid];
    red[tid] = s; __syncthreads();
    for (int st = 128; st > 0; st >>= 1) {
        if (tid < st) red[tid] += red[tid + st];
        __syncthreads();
    }
    if (tid == 0) out[0] = 1.0f / (1.0f + __expf(-(red[0] + b_lin[0])));
}

// ---------------------------------------------------------------------------
extern "C" void kernel_launch(void* const* d_in, const int* in_sizes, int n_in,
                              void* d_out, int out_size, void* d_ws, size_t ws_size,
                              hipStream_t stream) {
    const float* embedding = (const float*)d_in[0];
    const float* w_ih      = (const float*)d_in[1];
    const float* w_hh      = (const float*)d_in[2];
    const float* b_ih      = (const float*)d_in[3];
    const float* b_hh      = (const float*)d_in[4];
    const float* w_lin     = (const float*)d_in[5];
    const float* b_lin     = (const float*)d_in[6];
    const int*   paths     = (const int*)d_in[7];
    const int*   user_id   = (const int*)d_in[8];
    const int*   item_id   = (const int*)d_in[9];
    float* outp = (float*)d_out;

    // workspace layout (~25.1 MB), 256-B aligned
    char* ws = (char*)d_ws;
    size_t off = 0;
    auto alloc = [&](size_t n) { void* p = ws + off; off = (off + n + 255) & ~(size_t)255; return p; };
    unsigned short* WfB       = (unsigned short*)alloc((size_t)1024 * 512 * 2);           // 1 MB
    float*          bias      = (float*)alloc(1024 * 4);                                  // 4 KB
    unsigned int*   logits_enc= (unsigned int*)alloc(NPATHS * 4);                         // 16 KB
    float*          path_emb  = (float*)alloc(HID * 4);                                   // 1 KB
    unsigned short* Xb        = (unsigned short*)alloc((size_t)LPATH * NPATHS * DIM * 2); // 16 MB
    unsigned short* h_buf     = (unsigned short*)alloc((size_t)2 * NPATHS * HID * 2);     // 4 MB
    float*          c_g       = (float*)alloc((size_t)NPATHS * HID * 4);                  // 4 MB

    prep_gather<<<8704, 256, 0, stream>>>(w_ih, w_hh, b_ih, b_hh, embedding, paths,
                                          WfB, bias, logits_enc, path_emb, Xb);

    for (int t = 0; t < LPATH; ++t) {
        const unsigned short* hin = h_buf + (size_t)(t & 1) * NPATHS * HID;
        unsigned short*      hout = h_buf + (size_t)((t + 1) & 1) * NPATHS * HID;
        if (t == 0)
            step_kernel<true, false><<<256, 256, 0, stream>>>(Xb, WfB, bias, hin, hout,
                                                              c_g, logits_enc, t);
        else if (t == LPATH - 1)
            step_kernel<false, true><<<256, 256, 0, stream>>>(Xb, WfB, bias, hin, hout,
                                                              c_g, logits_enc, t);
        else
            step_kernel<false, false><<<256, 256, 0, stream>>>(Xb, WfB, bias, hin, hout,
                                                               c_g, logits_enc, t);
    }

    // final h is in h_buf plane 0 (8 steps of ping-pong)
    attn_sum_kernel<<<NPATHS / 16, 256, 0, stream>>>(h_buf, logits_enc, path_emb);
    final_kernel<<<1, 256, 0, stream>>>(embedding, user_id, item_id, w_lin, b_lin,
                                        path_emb, outp);
}